// Round 15
// baseline (1156.840 us; speedup 1.0000x reference)
//
#include <hip/hip_runtime.h>

#define H    128
#define RBF  50
#define K1   64     // stage-1 K padded 50 -> 64 (cols 50-63 zero in weights; 56-59 carry src/dst)
#define EB   64     // edges per tile
#define NB   32
#define NBLK 1024   // 4 blocks/CU exactly

typedef _Float16 f16;
typedef _Float16 f16x8 __attribute__((ext_vector_type(8)));
typedef float    f32x4 __attribute__((ext_vector_type(4)));
typedef float    fv4   __attribute__((ext_vector_type(4)));   // ext-vector floats for nontemporal builtins
typedef float    fv2   __attribute__((ext_vector_type(2)));

#define HS_LD 136   // h_s row stride (f16): 272B

__device__ __forceinline__ float silu_f(float a) {
    return a / (1.0f + __expf(-a));
}

// ---------------- prep1: compute_h + convert_weights + hist (grid-partitioned) ----------------

__global__ __launch_bounds__(256) void prep1_kernel(
    const float* __restrict__ x, const float* __restrict__ dW,
    const float* __restrict__ db, f16* __restrict__ h, int N, int nH,
    const float* __restrict__ fW1, const float* __restrict__ fW2,
    f16* __restrict__ Wt1, f16* __restrict__ Wt2,
    const int* __restrict__ dst, int* __restrict__ counts, int E)
{
    __shared__ float xs[NB][H];
    const int tid = threadIdx.x;
    const int b   = blockIdx.x;

    if (b < nH) {
        const int n0 = b * NB;
        for (int idx = tid; idx < NB * H; idx += 256) {
            int r = idx >> 7, c = idx & (H - 1);
            int n = n0 + r;
            xs[r][c] = (n < N) ? x[(size_t)n * H + c] : 0.f;
        }
        __syncthreads();
        const int j  = tid & (H - 1);
        const int rb = (tid >> 7) * 16;
        float acc[16];
        const float bb = db[j];
#pragma unroll
        for (int r = 0; r < 16; ++r) acc[r] = bb;
        for (int kq = 0; kq < H / 4; ++kq) {
            const int k = kq * 4;
            const float w0 = dW[(k + 0) * H + j];
            const float w1 = dW[(k + 1) * H + j];
            const float w2 = dW[(k + 2) * H + j];
            const float w3 = dW[(k + 3) * H + j];
#pragma unroll
            for (int r = 0; r < 16; ++r) {
                const float4 v = *(const float4*)&xs[rb + r][k];
                acc[r] = fmaf(v.x, w0, fmaf(v.y, w1, fmaf(v.z, w2, fmaf(v.w, w3, acc[r]))));
            }
        }
#pragma unroll
        for (int r = 0; r < 16; ++r) {
            int n = n0 + rb + r;
            if (n < N) h[(size_t)n * H + j] = (f16)acc[r];
        }
    } else if (b < nH + 96) {
        int i = (b - nH) * 256 + tid;
        if (i < H * K1) {
            int n = i >> 6, k = i & (K1 - 1);
            Wt1[i] = (k < RBF) ? (f16)fW1[k * H + n] : (f16)0.f;
        }
        int jj = i - H * K1;
        if (jj >= 0 && jj < H * H) {
            int n = jj >> 7, k = jj & (H - 1);
            Wt2[jj] = (f16)fW2[k * H + n];
        }
    } else {
        const int hb  = b - nH - 96;
        const int hgd = gridDim.x - nH - 96;
        for (int i = hb * 256 + tid; i < E; i += hgd * 256)
            atomicAdd(&counts[dst[i]], 1);
    }
}

// ---------------- scan (3-phase) ----------------

__global__ __launch_bounds__(256) void scan1_kernel(
    const int* __restrict__ counts, int* __restrict__ ofs, int* __restrict__ bsum, int N)
{
    __shared__ int s[256];
    const int t = threadIdx.x;
    const int g = blockIdx.x * 256 + t;
    int v = (g < N) ? counts[g] : 0;
    s[t] = v; __syncthreads();
    for (int off = 1; off < 256; off <<= 1) {
        int u = 0; if (t >= off) u = s[t - off];
        __syncthreads(); s[t] += u; __syncthreads();
    }
    if (g < N) ofs[g] = s[t] - v;
    if (t == 255) bsum[blockIdx.x] = s[255];
}
__global__ __launch_bounds__(256) void scan2_kernel(int* __restrict__ bsum, int nb)
{
    __shared__ int s[256];
    const int t = threadIdx.x;
    int v = (t < nb) ? bsum[t] : 0;
    s[t] = v; __syncthreads();
    for (int off = 1; off < 256; off <<= 1) {
        int u = 0; if (t >= off) u = s[t - off];
        __syncthreads(); s[t] += u; __syncthreads();
    }
    if (t < nb) bsum[t] = s[t] - v;
}
__global__ __launch_bounds__(256) void scan3_kernel(
    int* __restrict__ ofs, int* __restrict__ cursor, const int* __restrict__ bsum, int N)
{
    int g = blockIdx.x * 256 + threadIdx.x;
    if (g < N) {
        int v = ofs[g] + bsum[blockIdx.x];
        ofs[g] = v;
        cursor[g] = v;
    }
}

// block ranges cut at node boundaries near b*E/B edges
__global__ __launch_bounds__(256) void ranges_kernel(
    const int* __restrict__ ofs, int* __restrict__ nstart, int* __restrict__ estart,
    int N, int E, int B)
{
    int b = blockIdx.x * 256 + threadIdx.x;
    if (b > B) return;
    if (b == B) { nstart[B] = N; estart[B] = E; return; }
    long long cb = (long long)b * E / B;
    int lo = 0, hi = N;
    while (lo < hi) {
        int mid = (lo + hi) >> 1;
        int val = (mid < N) ? ofs[mid] : E;
        if (val < (int)cb) lo = mid + 1; else hi = mid;
    }
    nstart[b] = lo;
    estart[b] = (lo < N) ? ofs[lo] : E;
}

// ---------------- build: scatter + ea convert, src/dst PACKED into row padding ----------------
__global__ __launch_bounds__(256) void build_kernel(
    const float* __restrict__ ea, const int* __restrict__ src, const int* __restrict__ dst,
    int* __restrict__ cursor, f16* __restrict__ ea16, int E)
{
    for (int e = blockIdx.x * 256 + threadIdx.x; e < E; e += gridDim.x * 256) {
        const int d  = dst[e];
        const int sV = src[e];
        const int pos = atomicAdd(&cursor[d], 1);

        const float* rp = ea + (size_t)e * RBF;
        f16* op = ea16 + (size_t)pos * K1;
        f16x8 v[8];
#pragma unroll
        for (int q = 0; q < 6; ++q) {
            const fv4 a = __builtin_nontemporal_load((const fv4*)(rp + q * 8));
            const fv4 b = __builtin_nontemporal_load((const fv4*)(rp + q * 8 + 4));
            f16x8 t;
            t[0]=(f16)a.x; t[1]=(f16)a.y; t[2]=(f16)a.z; t[3]=(f16)a.w;
            t[4]=(f16)b.x; t[5]=(f16)b.y; t[6]=(f16)b.z; t[7]=(f16)b.w;
            v[q] = t;
        }
        {
            const fv2 a = __builtin_nontemporal_load((const fv2*)(rp + 48));
            f16x8 t = {};
            t[0]=(f16)a.x; t[1]=(f16)a.y;
            v[6] = t;
        }
        {
            f16x8 t = {};                 // cols 56-63: src @56-57, dst @58-59, rest 0
            ((int*)&t)[0] = sV;
            ((int*)&t)[1] = d;
            v[7] = t;
        }
#pragma unroll
        for (int q = 0; q < 8; ++q)
            __builtin_nontemporal_store(v[q], (f16x8*)(op + q * 8));
    }
}

// ---------------- fused edge kernel: packed sd, ev prefetch, wc-batched out writes ----------------
__global__ __launch_bounds__(256, 4) void edge_fused_kernel(
    const f16* __restrict__ ea16,
    const f16* __restrict__ Wt1, const f16* __restrict__ Wt2,
    const float* __restrict__ fb1, const float* __restrict__ fb2,
    const f16* __restrict__ h, float* __restrict__ out,
    const int* __restrict__ nstart, const int* __restrict__ estart)
{
    __shared__ __align__(16) f16 uni[8192];        // ea frags [0,8KB), t frags [0,16KB)
    __shared__ __align__(16) f16 h_s[EB * HS_LD];
    __shared__ int dst_s[EB];

    const int tid  = threadIdx.x;
    const int lane = tid & 63;
    const int wv   = tid >> 6;
    const int wr   = (wv >> 1) * 32;
    const int wc   = (wv & 1) * 64;
    const int fr   = lane & 15;
    const int qw   = lane >> 4;
    const int kb   = qw * 8;

    const int ch = tid & 7;       // staging chunk 0..7 (16B each = row 128B)

    // persistent B fragments
    f16x8 B1[4][2];
    f16x8 B2[4][4];
    float b1v[4], b2v[4];
#pragma unroll
    for (int ct = 0; ct < 4; ++ct) {
        const int col = wc + ct * 16 + fr;
#pragma unroll
        for (int ks = 0; ks < 2; ++ks)
            B1[ct][ks] = *(const f16x8*)&Wt1[col * K1 + ks * 32 + kb];
#pragma unroll
        for (int ks = 0; ks < 4; ++ks)
            B2[ct][ks] = *(const f16x8*)&Wt2[col * H + ks * 32 + kb];
        b1v[ct] = fb1[col];
        b2v[ct] = fb2[col];
    }

    const int ns = nstart[blockIdx.x], ne = nstart[blockIdx.x + 1];
    const int e0 = estart[blockIdx.x], e1 = estart[blockIdx.x + 1];

    const int col128 = tid & 127;

    if (e0 >= e1) {   // no edges: zero own node range
        for (int idx = tid; idx < (ne - ns) * H; idx += 256)
            out[(size_t)ns * H + idx] = 0.f;
        return;
    }

    // reduce state (tid<128): running sum + 4-row register write-combine buffer
    int   curdst = ns;
    float accv   = 0.f;
    int   wbase  = ns & ~3;
    float wc0 = 0.f, wc1 = 0.f, wc2 = 0.f, wc3 = 0.f;

#define FLUSH4 do { \
    if (wbase     >= ns && wbase     < ne) __builtin_nontemporal_store(wc0, &out[(size_t)(wbase    ) * H + col128]); \
    if (wbase + 1 >= ns && wbase + 1 < ne) __builtin_nontemporal_store(wc1, &out[(size_t)(wbase + 1) * H + col128]); \
    if (wbase + 2 >= ns && wbase + 2 < ne) __builtin_nontemporal_store(wc2, &out[(size_t)(wbase + 2) * H + col128]); \
    if (wbase + 3 >= ns && wbase + 3 < ne) __builtin_nontemporal_store(wc3, &out[(size_t)(wbase + 3) * H + col128]); \
    wc0 = wc1 = wc2 = wc3 = 0.f; } while (0)

    // prologue: prefetch ea16 chunks for tile 0
    f16x8 evC[2], evN[2];
#pragma unroll
    for (int i = 0; i < 2; ++i) {
        const int row = (tid >> 3) + i * 32;
        int pe = e0 + row; pe = (pe < e1) ? pe : (e1 - 1);
        evC[i] = __builtin_nontemporal_load((const f16x8*)(ea16 + (size_t)pe * K1 + ch * 8));
    }

    for (int tb = e0; tb < e1; tb += EB) {
        // ---- stage from evC: ea frags -> uni, extract src/dst via shfl, h gather -> h_s ----
#pragma unroll
        for (int i = 0; i < 2; ++i) {
            const int row = (tid >> 3) + i * 32;
            const int sp = ((int*)&evC[i])[0];
            const int dp = ((int*)&evC[i])[1];
            const int srcv = __shfl(sp, lane | 7);
            const int dstv = __shfl(dp, lane | 7);
            f16x8 w = evC[i];
            if (ch == 7) { w[0] = (f16)0.f; w[1] = (f16)0.f; w[2] = (f16)0.f; w[3] = (f16)0.f; }
            *(f16x8*)((char*)uni + (size_t)((ch * 64 + row) * 16)) = w;
            const f16* hp = h + (size_t)srcv * H;
            *(f16x8*)&h_s[row * HS_LD + ch * 8]      = *(const f16x8*)(hp + ch * 8);
            *(f16x8*)&h_s[row * HS_LD + 64 + ch * 8] = *(const f16x8*)(hp + 64 + ch * 8);
            if (ch == 7) dst_s[row] = (tb + row < e1) ? dstv : ne;
        }
        __syncthreads();   // B1: ea + h_s + dst_s visible

        // ---- prefetch next tile's ea16 (hides under MFMA/silu) ----
#pragma unroll
        for (int i = 0; i < 2; ++i) {
            const int row = (tid >> 3) + i * 32;
            int pe = tb + EB + row; pe = (pe < e1) ? pe : (e1 - 1);
            evN[i] = __builtin_nontemporal_load((const f16x8*)(ea16 + (size_t)pe * K1 + ch * 8));
        }

        // ---- stage 1 MFMA: t = ea @ W1 + b1 ----
        f32x4 acc1[2][4];
#pragma unroll
        for (int rt = 0; rt < 2; ++rt)
#pragma unroll
            for (int ct = 0; ct < 4; ++ct)
                acc1[rt][ct] = (f32x4){b1v[ct], b1v[ct], b1v[ct], b1v[ct]};
#pragma unroll
        for (int ks = 0; ks < 2; ++ks) {
            const f16x8 A0 = *(const f16x8*)((char*)uni + (size_t)(((ks * 4 + qw) * 64 + wr + fr) * 16));
            const f16x8 A1 = *(const f16x8*)((char*)uni + (size_t)(((ks * 4 + qw) * 64 + wr + 16 + fr) * 16));
#pragma unroll
            for (int ct = 0; ct < 4; ++ct) {
                acc1[0][ct] = __builtin_amdgcn_mfma_f32_16x16x32_f16(A0, B1[ct][ks], acc1[0][ct], 0, 0, 0);
                acc1[1][ct] = __builtin_amdgcn_mfma_f32_16x16x32_f16(A1, B1[ct][ks], acc1[1][ct], 0, 0, 0);
            }
        }
        __syncthreads();   // B2: ea reads done before t overwrites union

        // ---- silu -> t frags ----
#pragma unroll
        for (int rt = 0; rt < 2; ++rt)
#pragma unroll
            for (int ct = 0; ct < 4; ++ct)
#pragma unroll
                for (int m = 0; m < 4; ++m) {
                    const int er = wr + rt * 16 + qw * 4 + m;
                    const int c  = wc + ct * 16 + fr;
                    *(f16*)((char*)uni + (size_t)(((c >> 3) * 64 + er) * 16 + (c & 7) * 2)) =
                        (f16)silu_f(acc1[rt][ct][m]);
                }
        __syncthreads();   // B3: t visible

        // ---- stage 2 MFMA: filt = t @ W2 + b2 ----
        f32x4 acc2[2][4];
#pragma unroll
        for (int rt = 0; rt < 2; ++rt)
#pragma unroll
            for (int ct = 0; ct < 4; ++ct)
                acc2[rt][ct] = (f32x4){b2v[ct], b2v[ct], b2v[ct], b2v[ct]};
#pragma unroll
        for (int ks = 0; ks < 4; ++ks) {
            const f16x8 A0 = *(const f16x8*)((char*)uni + (size_t)(((ks * 4 + qw) * 64 + wr + fr) * 16));
            const f16x8 A1 = *(const f16x8*)((char*)uni + (size_t)(((ks * 4 + qw) * 64 + wr + 16 + fr) * 16));
#pragma unroll
            for (int ct = 0; ct < 4; ++ct) {
                acc2[0][ct] = __builtin_amdgcn_mfma_f32_16x16x32_f16(A0, B2[ct][ks], acc2[0][ct], 0, 0, 0);
                acc2[1][ct] = __builtin_amdgcn_mfma_f32_16x16x32_f16(A1, B2[ct][ks], acc2[1][ct], 0, 0, 0);
            }
        }

        // ---- msg = h * filt, in place in h_s ----
#pragma unroll
        for (int rt = 0; rt < 2; ++rt)
#pragma unroll
            for (int ct = 0; ct < 4; ++ct)
#pragma unroll
                for (int m = 0; m < 4; ++m) {
                    const int er = wr + rt * 16 + qw * 4 + m;
                    const int c  = wc + ct * 16 + fr;
                    f16* p = &h_s[er * HS_LD + c];
                    *p = (f16)((float)*p * acc2[rt][ct][m]);
                }
        __syncthreads();   // B4: msg visible

        // ---- segmented reduce -> register write-combine buffer (tid<128) ----
        if (tid < 128) {
            for (int r = 0; r < EB; ++r) {
                const int d = dst_s[r];
                const float v = (float)h_s[r * HS_LD + col128];
                if (d != curdst) {
                    if (curdst < ne) {
                        while (curdst >= wbase + 4) { FLUSH4; wbase += 4; }
                        const int sl = curdst - wbase;
                        if      (sl == 0) wc0 = accv;
                        else if (sl == 1) wc1 = accv;
                        else if (sl == 2) wc2 = accv;
                        else              wc3 = accv;
                    }
                    curdst = d; accv = 0.f;
                }
                if (d < ne) accv += v;
            }
        }
        __syncthreads();   // B5: reduce done before next staging overwrites h_s/uni/dst_s

        evC[0] = evN[0]; evC[1] = evN[1];
    }

    // ---- epilogue: final emit + flush + trailing zero-fill ----
    if (tid < 128) {
        if (curdst < ne) {
            while (curdst >= wbase + 4) { FLUSH4; wbase += 4; }
            const int sl = curdst - wbase;
            if      (sl == 0) wc0 = accv;
            else if (sl == 1) wc1 = accv;
            else if (sl == 2) wc2 = accv;
            else              wc3 = accv;
        }
        FLUSH4;
        for (int n = wbase + 4; n < ne; ++n)
            __builtin_nontemporal_store(0.f, &out[(size_t)n * H + col128]);
    }
#undef FLUSH4
}

// out = x + silu(agg@uW1+ub1)@uW2+ub2 ; agg lives in `out` on entry
__global__ __launch_bounds__(256) void update_kernel(
    const float* __restrict__ x,
    const float* __restrict__ uW1, const float* __restrict__ ub1,
    const float* __restrict__ uW2, const float* __restrict__ ub2,
    float* __restrict__ out, int N)
{
    __shared__ float as[NB][H];
    __shared__ float ts[NB][H];
    const int tid = threadIdx.x;
    const int n0  = blockIdx.x * NB;
    for (int idx = tid; idx < NB * H; idx += 256) {
        int r = idx >> 7, c = idx & (H - 1);
        int n = n0 + r;
        as[r][c] = (n < N) ? out[(size_t)n * H + c] : 0.f;
    }
    __syncthreads();
    const int j  = tid & (H - 1);
    const int rb = (tid >> 7) * 16;
    float acc[16];
    {
        const float b1 = ub1[j];
#pragma unroll
        for (int r = 0; r < 16; ++r) acc[r] = b1;
    }
    for (int kq = 0; kq < H / 4; ++kq) {
        const int k = kq * 4;
        const float w0 = uW1[(k + 0) * H + j];
        const float w1 = uW1[(k + 1) * H + j];
        const float w2 = uW1[(k + 2) * H + j];
        const float w3 = uW1[(k + 3) * H + j];
#pragma unroll
        for (int r = 0; r < 16; ++r) {
            const float4 v = *(const float4*)&as[rb + r][k];
            acc[r] = fmaf(v.x, w0, fmaf(v.y, w1, fmaf(v.z, w2, fmaf(v.w, w3, acc[r]))));
        }
    }
#pragma unroll
    for (int r = 0; r < 16; ++r) ts[rb + r][j] = silu_f(acc[r]);
    __syncthreads();
    {
        const float b2 = ub2[j];
#pragma unroll
        for (int r = 0; r < 16; ++r) acc[r] = b2;
    }
    for (int kq = 0; kq < H / 4; ++kq) {
        const int k = kq * 4;
        const float w0 = uW2[(k + 0) * H + j];
        const float w1 = uW2[(k + 1) * H + j];
        const float w2 = uW2[(k + 2) * H + j];
        const float w3 = uW2[(k + 3) * H + j];
#pragma unroll
        for (int r = 0; r < 16; ++r) {
            const float4 v = *(const float4*)&ts[rb + r][k];
            acc[r] = fmaf(v.x, w0, fmaf(v.y, w1, fmaf(v.z, w2, fmaf(v.w, w3, acc[r]))));
        }
    }
#pragma unroll
    for (int r = 0; r < 16; ++r) {
        int n = n0 + rb + r;
        if (n < N) out[(size_t)n * H + j] = x[(size_t)n * H + j] + acc[r];
    }
}

extern "C" void kernel_launch(void* const* d_in, const int* in_sizes, int n_in,
                              void* d_out, int out_size, void* d_ws, size_t ws_size,
                              hipStream_t stream) {
    const float* x   = (const float*)d_in[0];
    const int*   ei  = (const int*)  d_in[1];
    const float* ea  = (const float*)d_in[2];
    const float* fW1 = (const float*)d_in[3];
    const float* fb1 = (const float*)d_in[4];
    const float* fW2 = (const float*)d_in[5];
    const float* fb2 = (const float*)d_in[6];
    const float* dW  = (const float*)d_in[7];
    const float* db  = (const float*)d_in[8];
    const float* uW1 = (const float*)d_in[9];
    const float* ub1 = (const float*)d_in[10];
    const float* uW2 = (const float*)d_in[11];
    const float* ub2 = (const float*)d_in[12];

    float* out = (float*)d_out;
    const int N = in_sizes[0] / H;
    const int E = in_sizes[1] / 2;
    const int* src = ei;
    const int* dst = ei + E;

    char* ws = (char*)d_ws;
    size_t off = 0;
    auto alloc = [&](size_t bytes) { void* p = ws + off; off = (off + bytes + 255) & ~(size_t)255; return p; };
    f16*  h      = (f16*) alloc((size_t)N * H * sizeof(f16));
    f16*  Wt1    = (f16*) alloc((size_t)H * K1 * sizeof(f16));
    f16*  Wt2    = (f16*) alloc((size_t)H * H * sizeof(f16));
    int*  counts = (int*) alloc((size_t)N * sizeof(int));
    int*  ofs    = (int*) alloc((size_t)N * sizeof(int));
    int*  cursor = (int*) alloc((size_t)N * sizeof(int));
    int*  bsum   = (int*) alloc(256 * sizeof(int));
    int*  nstart = (int*) alloc((size_t)(NBLK + 1) * sizeof(int));
    int*  estart = (int*) alloc((size_t)(NBLK + 1) * sizeof(int));
    f16*  ea16   = (f16*) alloc((size_t)E * K1 * sizeof(f16));

    const int nH    = (N + NB - 1) / NB;
    const int nscan = (N + 255) / 256;

    hipMemsetAsync(counts, 0, (size_t)N * sizeof(int), stream);

    prep1_kernel<<<nH + 96 + 2048, 256, 0, stream>>>(
        x, dW, db, h, N, nH, fW1, fW2, Wt1, Wt2, dst, counts, E);

    scan1_kernel<<<nscan, 256, 0, stream>>>(counts, ofs, bsum, N);
    scan2_kernel<<<1, 256, 0, stream>>>(bsum, nscan);
    scan3_kernel<<<nscan, 256, 0, stream>>>(ofs, cursor, bsum, N);

    ranges_kernel<<<(NBLK + 256) / 256, 256, 0, stream>>>(ofs, nstart, estart, N, E, NBLK);

    build_kernel<<<2048, 256, 0, stream>>>(ea, src, dst, cursor, ea16, E);

    edge_fused_kernel<<<NBLK, 256, 0, stream>>>(
        ea16, Wt1, Wt2, fb1, fb2, h, out, nstart, estart);

    update_kernel<<<nH, 256, 0, stream>>>(
        x, uW1, ub1, uW2, ub2, out, N);
}

// Round 16
// 972.408 us; speedup vs baseline: 1.1897x; 1.1897x over previous
//
#include <hip/hip_runtime.h>

#define H    128
#define RBF  50
#define K1   64     // stage-1 K padded 50 -> 64 (cols 50-63 zero in weights; 56-59 carry src/dst)
#define EB   64     // edges per tile
#define NB   32
#define NBLK 1024   // 4 blocks/CU exactly

typedef _Float16 f16;
typedef _Float16 f16x8 __attribute__((ext_vector_type(8)));
typedef float    f32x4 __attribute__((ext_vector_type(4)));

#define HS_LD 136   // h_s row stride (f16): 272B

__device__ __forceinline__ float silu_f(float a) {
    return a / (1.0f + __expf(-a));
}

// ---------------- prep1: compute_h + convert_weights + hist (grid-partitioned) ----------------

__global__ __launch_bounds__(256) void prep1_kernel(
    const float* __restrict__ x, const float* __restrict__ dW,
    const float* __restrict__ db, f16* __restrict__ h, int N, int nH,
    const float* __restrict__ fW1, const float* __restrict__ fW2,
    f16* __restrict__ Wt1, f16* __restrict__ Wt2,
    const int* __restrict__ dst, int* __restrict__ counts, int E)
{
    __shared__ float xs[NB][H];
    const int tid = threadIdx.x;
    const int b   = blockIdx.x;

    if (b < nH) {
        const int n0 = b * NB;
        for (int idx = tid; idx < NB * H; idx += 256) {
            int r = idx >> 7, c = idx & (H - 1);
            int n = n0 + r;
            xs[r][c] = (n < N) ? x[(size_t)n * H + c] : 0.f;
        }
        __syncthreads();
        const int j  = tid & (H - 1);
        const int rb = (tid >> 7) * 16;
        float acc[16];
        const float bb = db[j];
#pragma unroll
        for (int r = 0; r < 16; ++r) acc[r] = bb;
        for (int kq = 0; kq < H / 4; ++kq) {
            const int k = kq * 4;
            const float w0 = dW[(k + 0) * H + j];
            const float w1 = dW[(k + 1) * H + j];
            const float w2 = dW[(k + 2) * H + j];
            const float w3 = dW[(k + 3) * H + j];
#pragma unroll
            for (int r = 0; r < 16; ++r) {
                const float4 v = *(const float4*)&xs[rb + r][k];
                acc[r] = fmaf(v.x, w0, fmaf(v.y, w1, fmaf(v.z, w2, fmaf(v.w, w3, acc[r]))));
            }
        }
#pragma unroll
        for (int r = 0; r < 16; ++r) {
            int n = n0 + rb + r;
            if (n < N) h[(size_t)n * H + j] = (f16)acc[r];
        }
    } else if (b < nH + 96) {
        int i = (b - nH) * 256 + tid;
        if (i < H * K1) {
            int n = i >> 6, k = i & (K1 - 1);
            Wt1[i] = (k < RBF) ? (f16)fW1[k * H + n] : (f16)0.f;
        }
        int jj = i - H * K1;
        if (jj >= 0 && jj < H * H) {
            int n = jj >> 7, k = jj & (H - 1);
            Wt2[jj] = (f16)fW2[k * H + n];
        }
    } else {
        const int hb  = b - nH - 96;
        const int hgd = gridDim.x - nH - 96;
        for (int i = hb * 256 + tid; i < E; i += hgd * 256)
            atomicAdd(&counts[dst[i]], 1);
    }
}

// ---------------- scan (3-phase) ----------------

__global__ __launch_bounds__(256) void scan1_kernel(
    const int* __restrict__ counts, int* __restrict__ ofs, int* __restrict__ bsum, int N)
{
    __shared__ int s[256];
    const int t = threadIdx.x;
    const int g = blockIdx.x * 256 + t;
    int v = (g < N) ? counts[g] : 0;
    s[t] = v; __syncthreads();
    for (int off = 1; off < 256; off <<= 1) {
        int u = 0; if (t >= off) u = s[t - off];
        __syncthreads(); s[t] += u; __syncthreads();
    }
    if (g < N) ofs[g] = s[t] - v;
    if (t == 255) bsum[blockIdx.x] = s[255];
}
__global__ __launch_bounds__(256) void scan2_kernel(int* __restrict__ bsum, int nb)
{
    __shared__ int s[256];
    const int t = threadIdx.x;
    int v = (t < nb) ? bsum[t] : 0;
    s[t] = v; __syncthreads();
    for (int off = 1; off < 256; off <<= 1) {
        int u = 0; if (t >= off) u = s[t - off];
        __syncthreads(); s[t] += u; __syncthreads();
    }
    if (t < nb) bsum[t] = s[t] - v;
}
__global__ __launch_bounds__(256) void scan3_kernel(
    int* __restrict__ ofs, int* __restrict__ cursor, const int* __restrict__ bsum, int N)
{
    int g = blockIdx.x * 256 + threadIdx.x;
    if (g < N) {
        int v = ofs[g] + bsum[blockIdx.x];
        ofs[g] = v;
        cursor[g] = v;
    }
}

// block ranges cut at node boundaries near b*E/B edges
__global__ __launch_bounds__(256) void ranges_kernel(
    const int* __restrict__ ofs, int* __restrict__ nstart, int* __restrict__ estart,
    int N, int E, int B)
{
    int b = blockIdx.x * 256 + threadIdx.x;
    if (b > B) return;
    if (b == B) { nstart[B] = N; estart[B] = E; return; }
    long long cb = (long long)b * E / B;
    int lo = 0, hi = N;
    while (lo < hi) {
        int mid = (lo + hi) >> 1;
        int val = (mid < N) ? ofs[mid] : E;
        if (val < (int)cb) lo = mid + 1; else hi = mid;
    }
    nstart[b] = lo;
    estart[b] = (lo < N) ? ofs[lo] : E;
}

// ---------------- build: scatter + ea convert, src/dst PACKED into row padding ----------------
__global__ __launch_bounds__(256) void build_kernel(
    const float* __restrict__ ea, const int* __restrict__ src, const int* __restrict__ dst,
    int* __restrict__ cursor, f16* __restrict__ ea16, int E)
{
    for (int e = blockIdx.x * 256 + threadIdx.x; e < E; e += gridDim.x * 256) {
        const int d  = dst[e];
        const int sV = src[e];
        const int pos = atomicAdd(&cursor[d], 1);

        const float* rp = ea + (size_t)e * RBF;
        f16* op = ea16 + (size_t)pos * K1;
        f16x8 v[8];
#pragma unroll
        for (int q = 0; q < 6; ++q) {
            const float4 a = *(const float4*)(rp + q * 8);
            const float4 b = *(const float4*)(rp + q * 8 + 4);
            f16x8 t;
            t[0]=(f16)a.x; t[1]=(f16)a.y; t[2]=(f16)a.z; t[3]=(f16)a.w;
            t[4]=(f16)b.x; t[5]=(f16)b.y; t[6]=(f16)b.z; t[7]=(f16)b.w;
            v[q] = t;
        }
        {
            const float2 a = *(const float2*)(rp + 48);
            f16x8 t = {};
            t[0]=(f16)a.x; t[1]=(f16)a.y;
            v[6] = t;
        }
        {
            f16x8 t = {};                 // cols 56-63: src @56-57, dst @58-59, rest 0
            ((int*)&t)[0] = sV;
            ((int*)&t)[1] = d;
            v[7] = t;
        }
#pragma unroll
        for (int q = 0; q < 8; ++q) *(f16x8*)(op + q * 8) = v[q];
    }
}

// ---------------- fused edge kernel: packed sd, ev prefetch, plain-store reduce ----------------
__global__ __launch_bounds__(256, 4) void edge_fused_kernel(
    const f16* __restrict__ ea16,
    const f16* __restrict__ Wt1, const f16* __restrict__ Wt2,
    const float* __restrict__ fb1, const float* __restrict__ fb2,
    const f16* __restrict__ h, float* __restrict__ out,
    const int* __restrict__ nstart, const int* __restrict__ estart)
{
    __shared__ __align__(16) f16 uni[8192];        // ea frags [0,8KB), t frags [0,16KB)
    __shared__ __align__(16) f16 h_s[EB * HS_LD];
    __shared__ int dst_s[EB];

    const int tid  = threadIdx.x;
    const int lane = tid & 63;
    const int wv   = tid >> 6;
    const int wr   = (wv >> 1) * 32;
    const int wc   = (wv & 1) * 64;
    const int fr   = lane & 15;
    const int qw   = lane >> 4;
    const int kb   = qw * 8;

    const int ch = tid & 7;       // staging chunk 0..7 (16B each = row 128B)

    // persistent B fragments
    f16x8 B1[4][2];
    f16x8 B2[4][4];
    float b1v[4], b2v[4];
#pragma unroll
    for (int ct = 0; ct < 4; ++ct) {
        const int col = wc + ct * 16 + fr;
#pragma unroll
        for (int ks = 0; ks < 2; ++ks)
            B1[ct][ks] = *(const f16x8*)&Wt1[col * K1 + ks * 32 + kb];
#pragma unroll
        for (int ks = 0; ks < 4; ++ks)
            B2[ct][ks] = *(const f16x8*)&Wt2[col * H + ks * 32 + kb];
        b1v[ct] = fb1[col];
        b2v[ct] = fb2[col];
    }

    const int ns = nstart[blockIdx.x], ne = nstart[blockIdx.x + 1];
    const int e0 = estart[blockIdx.x], e1 = estart[blockIdx.x + 1];

    const int col128 = tid & 127;

    if (e0 >= e1) {   // no edges: zero own node range
        for (int idx = tid; idx < (ne - ns) * H; idx += 256)
            out[(size_t)ns * H + idx] = 0.f;
        return;
    }

    int   curdst = ns;
    float accv   = 0.f;

    // prologue: prefetch ea16 chunks for tile 0
    f16x8 evC[2], evN[2];
#pragma unroll
    for (int i = 0; i < 2; ++i) {
        const int row = (tid >> 3) + i * 32;
        int pe = e0 + row; pe = (pe < e1) ? pe : (e1 - 1);
        evC[i] = *(const f16x8*)(ea16 + (size_t)pe * K1 + ch * 8);
    }

    for (int tb = e0; tb < e1; tb += EB) {
        // ---- stage from evC: ea frags -> uni, extract src/dst via shfl, h gather -> h_s ----
#pragma unroll
        for (int i = 0; i < 2; ++i) {
            const int row = (tid >> 3) + i * 32;
            const int sp = ((int*)&evC[i])[0];
            const int dp = ((int*)&evC[i])[1];
            const int srcv = __shfl(sp, lane | 7);
            const int dstv = __shfl(dp, lane | 7);
            f16x8 w = evC[i];
            if (ch == 7) { w[0] = (f16)0.f; w[1] = (f16)0.f; w[2] = (f16)0.f; w[3] = (f16)0.f; }
            *(f16x8*)((char*)uni + (size_t)((ch * 64 + row) * 16)) = w;
            const f16* hp = h + (size_t)srcv * H;
            *(f16x8*)&h_s[row * HS_LD + ch * 8]      = *(const f16x8*)(hp + ch * 8);
            *(f16x8*)&h_s[row * HS_LD + 64 + ch * 8] = *(const f16x8*)(hp + 64 + ch * 8);
            if (ch == 7) dst_s[row] = (tb + row < e1) ? dstv : ne;
        }
        __syncthreads();   // B1: ea + h_s + dst_s visible

        // ---- prefetch next tile's ea16 (hides under MFMA/silu) ----
#pragma unroll
        for (int i = 0; i < 2; ++i) {
            const int row = (tid >> 3) + i * 32;
            int pe = tb + EB + row; pe = (pe < e1) ? pe : (e1 - 1);
            evN[i] = *(const f16x8*)(ea16 + (size_t)pe * K1 + ch * 8);
        }

        // ---- stage 1 MFMA: t = ea @ W1 + b1 ----
        f32x4 acc1[2][4];
#pragma unroll
        for (int rt = 0; rt < 2; ++rt)
#pragma unroll
            for (int ct = 0; ct < 4; ++ct)
                acc1[rt][ct] = (f32x4){b1v[ct], b1v[ct], b1v[ct], b1v[ct]};
#pragma unroll
        for (int ks = 0; ks < 2; ++ks) {
            const f16x8 A0 = *(const f16x8*)((char*)uni + (size_t)(((ks * 4 + qw) * 64 + wr + fr) * 16));
            const f16x8 A1 = *(const f16x8*)((char*)uni + (size_t)(((ks * 4 + qw) * 64 + wr + 16 + fr) * 16));
#pragma unroll
            for (int ct = 0; ct < 4; ++ct) {
                acc1[0][ct] = __builtin_amdgcn_mfma_f32_16x16x32_f16(A0, B1[ct][ks], acc1[0][ct], 0, 0, 0);
                acc1[1][ct] = __builtin_amdgcn_mfma_f32_16x16x32_f16(A1, B1[ct][ks], acc1[1][ct], 0, 0, 0);
            }
        }
        __syncthreads();   // B2: ea reads done before t overwrites union

        // ---- silu -> t frags ----
#pragma unroll
        for (int rt = 0; rt < 2; ++rt)
#pragma unroll
            for (int ct = 0; ct < 4; ++ct)
#pragma unroll
                for (int m = 0; m < 4; ++m) {
                    const int er = wr + rt * 16 + qw * 4 + m;
                    const int c  = wc + ct * 16 + fr;
                    *(f16*)((char*)uni + (size_t)(((c >> 3) * 64 + er) * 16 + (c & 7) * 2)) =
                        (f16)silu_f(acc1[rt][ct][m]);
                }
        __syncthreads();   // B3: t visible

        // ---- stage 2 MFMA: filt = t @ W2 + b2 ----
        f32x4 acc2[2][4];
#pragma unroll
        for (int rt = 0; rt < 2; ++rt)
#pragma unroll
            for (int ct = 0; ct < 4; ++ct)
                acc2[rt][ct] = (f32x4){b2v[ct], b2v[ct], b2v[ct], b2v[ct]};
#pragma unroll
        for (int ks = 0; ks < 4; ++ks) {
            const f16x8 A0 = *(const f16x8*)((char*)uni + (size_t)(((ks * 4 + qw) * 64 + wr + fr) * 16));
            const f16x8 A1 = *(const f16x8*)((char*)uni + (size_t)(((ks * 4 + qw) * 64 + wr + 16 + fr) * 16));
#pragma unroll
            for (int ct = 0; ct < 4; ++ct) {
                acc2[0][ct] = __builtin_amdgcn_mfma_f32_16x16x32_f16(A0, B2[ct][ks], acc2[0][ct], 0, 0, 0);
                acc2[1][ct] = __builtin_amdgcn_mfma_f32_16x16x32_f16(A1, B2[ct][ks], acc2[1][ct], 0, 0, 0);
            }
        }

        // ---- msg = h * filt, in place in h_s ----
#pragma unroll
        for (int rt = 0; rt < 2; ++rt)
#pragma unroll
            for (int ct = 0; ct < 4; ++ct)
#pragma unroll
                for (int m = 0; m < 4; ++m) {
                    const int er = wr + rt * 16 + qw * 4 + m;
                    const int c  = wc + ct * 16 + fr;
                    f16* p = &h_s[er * HS_LD + c];
                    *p = (f16)((float)*p * acc2[rt][ct][m]);
                }
        __syncthreads();   // B4: msg visible

        // ---- segmented reduce over sorted dst rows: plain stores (R10-proven) ----
        if (tid < 128) {
            for (int r = 0; r < EB; ++r) {
                const int d = dst_s[r];
                const float v = (float)h_s[r * HS_LD + col128];
                if (d != curdst) {
                    out[(size_t)curdst * H + col128] = accv;
                    for (int n = curdst + 1; n < d; ++n) out[(size_t)n * H + col128] = 0.f;
                    curdst = d; accv = 0.f;
                }
                if (d < ne) accv += v;
            }
        }
        __syncthreads();   // B5: reduce done before next staging overwrites h_s/uni/dst_s

        evC[0] = evN[0]; evC[1] = evN[1];
    }

    if (tid < 128 && curdst < ne) {
        out[(size_t)curdst * H + col128] = accv;
        for (int n = curdst + 1; n < ne; ++n) out[(size_t)n * H + col128] = 0.f;
    }
}

// out = x + silu(agg@uW1+ub1)@uW2+ub2 ; agg lives in `out` on entry
__global__ __launch_bounds__(256) void update_kernel(
    const float* __restrict__ x,
    const float* __restrict__ uW1, const float* __restrict__ ub1,
    const float* __restrict__ uW2, const float* __restrict__ ub2,
    float* __restrict__ out, int N)
{
    __shared__ float as[NB][H];
    __shared__ float ts[NB][H];
    const int tid = threadIdx.x;
    const int n0  = blockIdx.x * NB;
    for (int idx = tid; idx < NB * H; idx += 256) {
        int r = idx >> 7, c = idx & (H - 1);
        int n = n0 + r;
        as[r][c] = (n < N) ? out[(size_t)n * H + c] : 0.f;
    }
    __syncthreads();
    const int j  = tid & (H - 1);
    const int rb = (tid >> 7) * 16;
    float acc[16];
    {
        const float b1 = ub1[j];
#pragma unroll
        for (int r = 0; r < 16; ++r) acc[r] = b1;
    }
    for (int kq = 0; kq < H / 4; ++kq) {
        const int k = kq * 4;
        const float w0 = uW1[(k + 0) * H + j];
        const float w1 = uW1[(k + 1) * H + j];
        const float w2 = uW1[(k + 2) * H + j];
        const float w3 = uW1[(k + 3) * H + j];
#pragma unroll
        for (int r = 0; r < 16; ++r) {
            const float4 v = *(const float4*)&as[rb + r][k];
            acc[r] = fmaf(v.x, w0, fmaf(v.y, w1, fmaf(v.z, w2, fmaf(v.w, w3, acc[r]))));
        }
    }
#pragma unroll
    for (int r = 0; r < 16; ++r) ts[rb + r][j] = silu_f(acc[r]);
    __syncthreads();
    {
        const float b2 = ub2[j];
#pragma unroll
        for (int r = 0; r < 16; ++r) acc[r] = b2;
    }
    for (int kq = 0; kq < H / 4; ++kq) {
        const int k = kq * 4;
        const float w0 = uW2[(k + 0) * H + j];
        const float w1 = uW2[(k + 1) * H + j];
        const float w2 = uW2[(k + 2) * H + j];
        const float w3 = uW2[(k + 3) * H + j];
#pragma unroll
        for (int r = 0; r < 16; ++r) {
            const float4 v = *(const float4*)&ts[rb + r][k];
            acc[r] = fmaf(v.x, w0, fmaf(v.y, w1, fmaf(v.z, w2, fmaf(v.w, w3, acc[r]))));
        }
    }
#pragma unroll
    for (int r = 0; r < 16; ++r) {
        int n = n0 + rb + r;
        if (n < N) out[(size_t)n * H + j] = x[(size_t)n * H + j] + acc[r];
    }
}

extern "C" void kernel_launch(void* const* d_in, const int* in_sizes, int n_in,
                              void* d_out, int out_size, void* d_ws, size_t ws_size,
                              hipStream_t stream) {
    const float* x   = (const float*)d_in[0];
    const int*   ei  = (const int*)  d_in[1];
    const float* ea  = (const float*)d_in[2];
    const float* fW1 = (const float*)d_in[3];
    const float* fb1 = (const float*)d_in[4];
    const float* fW2 = (const float*)d_in[5];
    const float* fb2 = (const float*)d_in[6];
    const float* dW  = (const float*)d_in[7];
    const float* db  = (const float*)d_in[8];
    const float* uW1 = (const float*)d_in[9];
    const float* ub1 = (const float*)d_in[10];
    const float* uW2 = (const float*)d_in[11];
    const float* ub2 = (const float*)d_in[12];

    float* out = (float*)d_out;
    const int N = in_sizes[0] / H;
    const int E = in_sizes[1] / 2;
    const int* src = ei;
    const int* dst = ei + E;

    char* ws = (char*)d_ws;
    size_t off = 0;
    auto alloc = [&](size_t bytes) { void* p = ws + off; off = (off + bytes + 255) & ~(size_t)255; return p; };
    f16*  h      = (f16*) alloc((size_t)N * H * sizeof(f16));
    f16*  Wt1    = (f16*) alloc((size_t)H * K1 * sizeof(f16));
    f16*  Wt2    = (f16*) alloc((size_t)H * H * sizeof(f16));
    int*  counts = (int*) alloc((size_t)N * sizeof(int));
    int*  ofs    = (int*) alloc((size_t)N * sizeof(int));
    int*  cursor = (int*) alloc((size_t)N * sizeof(int));
    int*  bsum   = (int*) alloc(256 * sizeof(int));
    int*  nstart = (int*) alloc((size_t)(NBLK + 1) * sizeof(int));
    int*  estart = (int*) alloc((size_t)(NBLK + 1) * sizeof(int));
    f16*  ea16   = (f16*) alloc((size_t)E * K1 * sizeof(f16));

    const int nH    = (N + NB - 1) / NB;
    const int nscan = (N + 255) / 256;

    hipMemsetAsync(counts, 0, (size_t)N * sizeof(int), stream);

    prep1_kernel<<<nH + 96 + 2048, 256, 0, stream>>>(
        x, dW, db, h, N, nH, fW1, fW2, Wt1, Wt2, dst, counts, E);

    scan1_kernel<<<nscan, 256, 0, stream>>>(counts, ofs, bsum, N);
    scan2_kernel<<<1, 256, 0, stream>>>(bsum, nscan);
    scan3_kernel<<<nscan, 256, 0, stream>>>(ofs, cursor, bsum, N);

    ranges_kernel<<<(NBLK + 256) / 256, 256, 0, stream>>>(ofs, nstart, estart, N, E, NBLK);

    build_kernel<<<2048, 256, 0, stream>>>(ea, src, dst, cursor, ea16, E);

    edge_fused_kernel<<<NBLK, 256, 0, stream>>>(
        ea16, Wt1, Wt2, fb1, fb2, h, out, nstart, estart);

    update_kernel<<<nH, 256, 0, stream>>>(
        x, uW1, ub1, uW2, ub2, out, N);
}

// Round 17
// 888.005 us; speedup vs baseline: 1.3027x; 1.0950x over previous
//
#include <hip/hip_runtime.h>

#define H    128
#define RBF  50
#define K1   64     // stage-1 K padded 50 -> 64
#define EB   64     // edges per tile
#define NB   32
#define NBLK 1024   // 4 blocks/CU exactly

typedef _Float16 f16;
typedef _Float16 f16x8 __attribute__((ext_vector_type(8)));
typedef float    f32x4 __attribute__((ext_vector_type(4)));

#define HS_LD 136   // h_s row stride (f16): 272B

__device__ __forceinline__ float silu_f(float a) {
    return a / (1.0f + __expf(-a));
}

// ---------------- prep1: compute_h + convert_weights + hist (grid-partitioned) ----------------

__global__ __launch_bounds__(256) void prep1_kernel(
    const float* __restrict__ x, const float* __restrict__ dW,
    const float* __restrict__ db, f16* __restrict__ h, int N, int nH,
    const float* __restrict__ fW1, const float* __restrict__ fW2,
    f16* __restrict__ Wt1, f16* __restrict__ Wt2,
    const int* __restrict__ dst, int* __restrict__ counts, int E)
{
    __shared__ float xs[NB][H];
    const int tid = threadIdx.x;
    const int b   = blockIdx.x;

    if (b < nH) {
        // ---- compute h = x @ dW + db (f16 store) ----
        const int n0 = b * NB;
        for (int idx = tid; idx < NB * H; idx += 256) {
            int r = idx >> 7, c = idx & (H - 1);
            int n = n0 + r;
            xs[r][c] = (n < N) ? x[(size_t)n * H + c] : 0.f;
        }
        __syncthreads();
        const int j  = tid & (H - 1);
        const int rb = (tid >> 7) * 16;
        float acc[16];
        const float bb = db[j];
#pragma unroll
        for (int r = 0; r < 16; ++r) acc[r] = bb;
        for (int kq = 0; kq < H / 4; ++kq) {
            const int k = kq * 4;
            const float w0 = dW[(k + 0) * H + j];
            const float w1 = dW[(k + 1) * H + j];
            const float w2 = dW[(k + 2) * H + j];
            const float w3 = dW[(k + 3) * H + j];
#pragma unroll
            for (int r = 0; r < 16; ++r) {
                const float4 v = *(const float4*)&xs[rb + r][k];
                acc[r] = fmaf(v.x, w0, fmaf(v.y, w1, fmaf(v.z, w2, fmaf(v.w, w3, acc[r]))));
            }
        }
#pragma unroll
        for (int r = 0; r < 16; ++r) {
            int n = n0 + rb + r;
            if (n < N) h[(size_t)n * H + j] = (f16)acc[r];
        }
    } else if (b < nH + 96) {
        // ---- convert weights (transposed f16, K1-padded) ----
        int i = (b - nH) * 256 + tid;
        if (i < H * K1) {
            int n = i >> 6, k = i & (K1 - 1);
            Wt1[i] = (k < RBF) ? (f16)fW1[k * H + n] : (f16)0.f;
        }
        int jj = i - H * K1;
        if (jj >= 0 && jj < H * H) {
            int n = jj >> 7, k = jj & (H - 1);
            Wt2[jj] = (f16)fW2[k * H + n];
        }
    } else {
        // ---- hist ----
        const int hb  = b - nH - 96;
        const int hgd = gridDim.x - nH - 96;
        for (int i = hb * 256 + tid; i < E; i += hgd * 256)
            atomicAdd(&counts[dst[i]], 1);
    }
}

// ---------------- scan (3-phase) ----------------

__global__ __launch_bounds__(256) void scan1_kernel(
    const int* __restrict__ counts, int* __restrict__ ofs, int* __restrict__ bsum, int N)
{
    __shared__ int s[256];
    const int t = threadIdx.x;
    const int g = blockIdx.x * 256 + t;
    int v = (g < N) ? counts[g] : 0;
    s[t] = v; __syncthreads();
    for (int off = 1; off < 256; off <<= 1) {
        int u = 0; if (t >= off) u = s[t - off];
        __syncthreads(); s[t] += u; __syncthreads();
    }
    if (g < N) ofs[g] = s[t] - v;
    if (t == 255) bsum[blockIdx.x] = s[255];
}
__global__ __launch_bounds__(256) void scan2_kernel(int* __restrict__ bsum, int nb)
{
    __shared__ int s[256];
    const int t = threadIdx.x;
    int v = (t < nb) ? bsum[t] : 0;
    s[t] = v; __syncthreads();
    for (int off = 1; off < 256; off <<= 1) {
        int u = 0; if (t >= off) u = s[t - off];
        __syncthreads(); s[t] += u; __syncthreads();
    }
    if (t < nb) bsum[t] = s[t] - v;
}
__global__ __launch_bounds__(256) void scan3_kernel(
    int* __restrict__ ofs, int* __restrict__ cursor, const int* __restrict__ bsum, int N)
{
    int g = blockIdx.x * 256 + threadIdx.x;
    if (g < N) {
        int v = ofs[g] + bsum[blockIdx.x];
        ofs[g] = v;
        cursor[g] = v;
    }
}

// block ranges cut at node boundaries near b*E/B edges
__global__ __launch_bounds__(256) void ranges_kernel(
    const int* __restrict__ ofs, int* __restrict__ nstart, int* __restrict__ estart,
    int N, int E, int B)
{
    int b = blockIdx.x * 256 + threadIdx.x;
    if (b > B) return;
    if (b == B) { nstart[B] = N; estart[B] = E; return; }
    long long cb = (long long)b * E / B;
    int lo = 0, hi = N;
    while (lo < hi) {
        int mid = (lo + hi) >> 1;
        int val = (mid < N) ? ofs[mid] : E;
        if (val < (int)cb) lo = mid + 1; else hi = mid;
    }
    nstart[b] = lo;
    estart[b] = (lo < N) ? ofs[lo] : E;
}

// ---------------- build: scatter + ea convert/permute in ONE pass ----------------
// per edge: pos = cursor[dst]++; sd[pos]={src,dst}; ea16[pos] = f16(ea[e]) padded to 128B
__global__ __launch_bounds__(256) void build_kernel(
    const float* __restrict__ ea, const int* __restrict__ src, const int* __restrict__ dst,
    int* __restrict__ cursor, int2* __restrict__ sd, f16* __restrict__ ea16, int E)
{
    for (int e = blockIdx.x * 256 + threadIdx.x; e < E; e += gridDim.x * 256) {
        const int d = dst[e];
        const int pos = atomicAdd(&cursor[d], 1);
        sd[pos] = make_int2(src[e], d);

        const float* rp = ea + (size_t)e * RBF;
        f16* op = ea16 + (size_t)pos * K1;
        f16x8 v[8];
#pragma unroll
        for (int q = 0; q < 6; ++q) {
            const float4 a = *(const float4*)(rp + q * 8);
            const float4 b = *(const float4*)(rp + q * 8 + 4);
            f16x8 t;
            t[0]=(f16)a.x; t[1]=(f16)a.y; t[2]=(f16)a.z; t[3]=(f16)a.w;
            t[4]=(f16)b.x; t[5]=(f16)b.y; t[6]=(f16)b.z; t[7]=(f16)b.w;
            v[q] = t;
        }
        {
            const float2 a = *(const float2*)(rp + 48);
            f16x8 t = {};
            t[0]=(f16)a.x; t[1]=(f16)a.y;
            v[6] = t;
        }
        v[7] = (f16x8){};
#pragma unroll
        for (int q = 0; q < 8; ++q) *(f16x8*)(op + q * 8) = v[q];
    }
}

// ---------------- fused edge kernel: full-line h gather, LDS sd staging, zero atomics ----------------
__global__ __launch_bounds__(256, 4) void edge_fused_kernel(
    const f16* __restrict__ ea16, const int2* __restrict__ sd,
    const f16* __restrict__ Wt1, const f16* __restrict__ Wt2,
    const float* __restrict__ fb1, const float* __restrict__ fb2,
    const f16* __restrict__ h, float* __restrict__ out,
    const int* __restrict__ nstart, const int* __restrict__ estart)
{
    // uni: ea frags [0,8KB), t frags [0,16KB) (time-shared, barriered)
    __shared__ __align__(16) f16 uni[8192];
    __shared__ __align__(16) f16 h_s[EB * HS_LD];
    __shared__ int src_s[2][EB];
    __shared__ int dst_s[2][EB];

    const int tid  = threadIdx.x;
    const int lane = tid & 63;
    const int wv   = tid >> 6;
    const int wr   = (wv >> 1) * 32;
    const int wc   = (wv & 1) * 64;
    const int fr   = lane & 15;
    const int qw   = lane >> 4;
    const int kb   = qw * 8;

    const int j = tid >> 2;   // ea tile row 0..63
    const int s = tid & 3;    // ea quarter

    // persistent B fragments
    f16x8 B1[4][2];
    f16x8 B2[4][4];
    float b1v[4], b2v[4];
#pragma unroll
    for (int ct = 0; ct < 4; ++ct) {
        const int col = wc + ct * 16 + fr;
#pragma unroll
        for (int ks = 0; ks < 2; ++ks)
            B1[ct][ks] = *(const f16x8*)&Wt1[col * K1 + ks * 32 + kb];
#pragma unroll
        for (int ks = 0; ks < 4; ++ks)
            B2[ct][ks] = *(const f16x8*)&Wt2[col * H + ks * 32 + kb];
        b1v[ct] = fb1[col];
        b2v[ct] = fb2[col];
    }

    const int ns = nstart[blockIdx.x], ne = nstart[blockIdx.x + 1];
    const int e0 = estart[blockIdx.x], e1 = estart[blockIdx.x + 1];

    if (e0 >= e1) {   // no edges: zero own node range
        for (int idx = tid; idx < (ne - ns) * H; idx += 256)
            out[(size_t)ns * H + idx] = 0.f;
        return;
    }

    const int col128 = tid & 127;
    int   curdst = ns;
    float accv   = 0.f;
    int   cur    = 0;

    // prologue: stage sd tile 0
    if (tid < EB) {
        int idx = e0 + tid; idx = (idx < e1) ? idx : (e1 - 1);
        int2 v = sd[idx];
        src_s[0][tid] = v.x;
        dst_s[0][tid] = (e0 + tid < e1) ? v.y : ne;
    }
    __syncthreads();

    for (int tb = e0; tb < e1; tb += EB) {
        // ---- stage: full-line h gather (8 lanes = 1 line/instr) + sequential ea16 (NT) ----
        {
#pragma unroll
            for (int i = 0; i < 2; ++i) {
                const int row = (tid >> 3) + i * 32;
                const int ch  = tid & 7;
                const f16* hp = h + (size_t)src_s[cur][row] * H;
#pragma unroll
                for (int half = 0; half < 2; ++half)
                    *(f16x8*)&h_s[row * HS_LD + half * 64 + ch * 8] =
                        *(const f16x8*)(hp + half * 64 + ch * 8);
            }
            const int pe = tb + j;
            const f16* ep = ea16 + (size_t)((pe < e1) ? pe : (e1 - 1)) * K1;
            // NT loads: stream ea16 without polluting L2 (keeps h rows resident)
            const f16x8 ev1 = __builtin_nontemporal_load((const f16x8*)(ep + s * 8));
            const f16x8 ev2 = __builtin_nontemporal_load((const f16x8*)(ep + 32 + s * 8));
            // frag layout: col c -> kblock c>>3; chunk1 = kblock s, chunk2 = kblock 4+s
            *(f16x8*)((char*)uni + (size_t)(((s)     * 64 + j) * 16)) = ev1;
            *(f16x8*)((char*)uni + (size_t)(((4 + s) * 64 + j) * 16)) = ev2;
        }
        __syncthreads();   // B1: ea + h_s visible

        // ---- stage 1 MFMA: t = ea @ W1 + b1 ----
        f32x4 acc1[2][4];
#pragma unroll
        for (int rt = 0; rt < 2; ++rt)
#pragma unroll
            for (int ct = 0; ct < 4; ++ct)
                acc1[rt][ct] = (f32x4){b1v[ct], b1v[ct], b1v[ct], b1v[ct]};
#pragma unroll
        for (int ks = 0; ks < 2; ++ks) {
            const f16x8 A0 = *(const f16x8*)((char*)uni + (size_t)(((ks * 4 + qw) * 64 + wr + fr) * 16));
            const f16x8 A1 = *(const f16x8*)((char*)uni + (size_t)(((ks * 4 + qw) * 64 + wr + 16 + fr) * 16));
#pragma unroll
            for (int ct = 0; ct < 4; ++ct) {
                acc1[0][ct] = __builtin_amdgcn_mfma_f32_16x16x32_f16(A0, B1[ct][ks], acc1[0][ct], 0, 0, 0);
                acc1[1][ct] = __builtin_amdgcn_mfma_f32_16x16x32_f16(A1, B1[ct][ks], acc1[1][ct], 0, 0, 0);
            }
        }
        __syncthreads();   // B2: ea reads done before t overwrites union

        // ---- silu -> t frags ----
#pragma unroll
        for (int rt = 0; rt < 2; ++rt)
#pragma unroll
            for (int ct = 0; ct < 4; ++ct)
#pragma unroll
                for (int m = 0; m < 4; ++m) {
                    const int er = wr + rt * 16 + qw * 4 + m;
                    const int c  = wc + ct * 16 + fr;
                    *(f16*)((char*)uni + (size_t)(((c >> 3) * 64 + er) * 16 + (c & 7) * 2)) =
                        (f16)silu_f(acc1[rt][ct][m]);
                }
        __syncthreads();   // B3: t visible

        // ---- stage 2 MFMA: filt = t @ W2 + b2 ----
        f32x4 acc2[2][4];
#pragma unroll
        for (int rt = 0; rt < 2; ++rt)
#pragma unroll
            for (int ct = 0; ct < 4; ++ct)
                acc2[rt][ct] = (f32x4){b2v[ct], b2v[ct], b2v[ct], b2v[ct]};
#pragma unroll
        for (int ks = 0; ks < 4; ++ks) {
            const f16x8 A0 = *(const f16x8*)((char*)uni + (size_t)(((ks * 4 + qw) * 64 + wr + fr) * 16));
            const f16x8 A1 = *(const f16x8*)((char*)uni + (size_t)(((ks * 4 + qw) * 64 + wr + 16 + fr) * 16));
#pragma unroll
            for (int ct = 0; ct < 4; ++ct) {
                acc2[0][ct] = __builtin_amdgcn_mfma_f32_16x16x32_f16(A0, B2[ct][ks], acc2[0][ct], 0, 0, 0);
                acc2[1][ct] = __builtin_amdgcn_mfma_f32_16x16x32_f16(A1, B2[ct][ks], acc2[1][ct], 0, 0, 0);
            }
        }

        // ---- msg = h * filt, in place in h_s ----
#pragma unroll
        for (int rt = 0; rt < 2; ++rt)
#pragma unroll
            for (int ct = 0; ct < 4; ++ct)
#pragma unroll
                for (int m = 0; m < 4; ++m) {
                    const int er = wr + rt * 16 + qw * 4 + m;
                    const int c  = wc + ct * 16 + fr;
                    f16* p = &h_s[er * HS_LD + c];
                    *p = (f16)((float)*p * acc2[rt][ct][m]);
                }
        __syncthreads();   // B4: msg visible

        // ---- reduce (tid<128)  ||  stage next sd tile (tid 128..191) ----
        if (tid < 128) {
            const int* ds = dst_s[cur];
            for (int r = 0; r < EB; ++r) {
                const int d = ds[r];
                const float v = (float)h_s[r * HS_LD + col128];
                if (d != curdst) {
                    out[(size_t)curdst * H + col128] = accv;
                    for (int n = curdst + 1; n < d; ++n) out[(size_t)n * H + col128] = 0.f;
                    curdst = d; accv = 0.f;
                }
                if (d < ne) accv += v;
            }
        } else if (tid < 128 + EB) {
            const int r = tid - 128;
            int idx = tb + EB + r; idx = (idx < e1) ? idx : (e1 - 1);
            int2 v = sd[idx];
            src_s[cur ^ 1][r] = v.x;
            dst_s[cur ^ 1][r] = (tb + EB + r < e1) ? v.y : ne;
        }
        __syncthreads();   // B5: reduce done + next sd visible before next staging

        cur ^= 1;
    }

    if (tid < 128 && curdst < ne) {
        out[(size_t)curdst * H + col128] = accv;
        for (int n = curdst + 1; n < ne; ++n) out[(size_t)n * H + col128] = 0.f;
    }
}

// out = x + silu(agg@uW1+ub1)@uW2+ub2 ; agg lives in `out` on entry
__global__ __launch_bounds__(256) void update_kernel(
    const float* __restrict__ x,
    const float* __restrict__ uW1, const float* __restrict__ ub1,
    const float* __restrict__ uW2, const float* __restrict__ ub2,
    float* __restrict__ out, int N)
{
    __shared__ float as[NB][H];
    __shared__ float ts[NB][H];
    const int tid = threadIdx.x;
    const int n0  = blockIdx.x * NB;
    for (int idx = tid; idx < NB * H; idx += 256) {
        int r = idx >> 7, c = idx & (H - 1);
        int n = n0 + r;
        as[r][c] = (n < N) ? out[(size_t)n * H + c] : 0.f;
    }
    __syncthreads();
    const int j  = tid & (H - 1);
    const int rb = (tid >> 7) * 16;
    float acc[16];
    {
        const float b1 = ub1[j];
#pragma unroll
        for (int r = 0; r < 16; ++r) acc[r] = b1;
    }
    for (int kq = 0; kq < H / 4; ++kq) {
        const int k = kq * 4;
        const float w0 = uW1[(k + 0) * H + j];
        const float w1 = uW1[(k + 1) * H + j];
        const float w2 = uW1[(k + 2) * H + j];
        const float w3 = uW1[(k + 3) * H + j];
#pragma unroll
        for (int r = 0; r < 16; ++r) {
            const float4 v = *(const float4*)&as[rb + r][k];
            acc[r] = fmaf(v.x, w0, fmaf(v.y, w1, fmaf(v.z, w2, fmaf(v.w, w3, acc[r]))));
        }
    }
#pragma unroll
    for (int r = 0; r < 16; ++r) ts[rb + r][j] = silu_f(acc[r]);
    __syncthreads();
    {
        const float b2 = ub2[j];
#pragma unroll
        for (int r = 0; r < 16; ++r) acc[r] = b2;
    }
    for (int kq = 0; kq < H / 4; ++kq) {
        const int k = kq * 4;
        const float w0 = uW2[(k + 0) * H + j];
        const float w1 = uW2[(k + 1) * H + j];
        const float w2 = uW2[(k + 2) * H + j];
        const float w3 = uW2[(k + 3) * H + j];
#pragma unroll
        for (int r = 0; r < 16; ++r) {
            const float4 v = *(const float4*)&ts[rb + r][k];
            acc[r] = fmaf(v.x, w0, fmaf(v.y, w1, fmaf(v.z, w2, fmaf(v.w, w3, acc[r]))));
        }
    }
#pragma unroll
    for (int r = 0; r < 16; ++r) {
        int n = n0 + rb + r;
        if (n < N) out[(size_t)n * H + j] = x[(size_t)n * H + j] + acc[r];
    }
}

extern "C" void kernel_launch(void* const* d_in, const int* in_sizes, int n_in,
                              void* d_out, int out_size, void* d_ws, size_t ws_size,
                              hipStream_t stream) {
    const float* x   = (const float*)d_in[0];
    const int*   ei  = (const int*)  d_in[1];
    const float* ea  = (const float*)d_in[2];
    const float* fW1 = (const float*)d_in[3];
    const float* fb1 = (const float*)d_in[4];
    const float* fW2 = (const float*)d_in[5];
    const float* fb2 = (const float*)d_in[6];
    const float* dW  = (const float*)d_in[7];
    const float* db  = (const float*)d_in[8];
    const float* uW1 = (const float*)d_in[9];
    const float* ub1 = (const float*)d_in[10];
    const float* uW2 = (const float*)d_in[11];
    const float* ub2 = (const float*)d_in[12];

    float* out = (float*)d_out;
    const int N = in_sizes[0] / H;
    const int E = in_sizes[1] / 2;
    const int* src = ei;
    const int* dst = ei + E;

    char* ws = (char*)d_ws;
    size_t off = 0;
    auto alloc = [&](size_t bytes) { void* p = ws + off; off = (off + bytes + 255) & ~(size_t)255; return p; };
    f16*  h      = (f16*) alloc((size_t)N * H * sizeof(f16));
    f16*  Wt1    = (f16*) alloc((size_t)H * K1 * sizeof(f16));
    f16*  Wt2    = (f16*) alloc((size_t)H * H * sizeof(f16));
    int*  counts = (int*) alloc((size_t)N * sizeof(int));
    int*  ofs    = (int*) alloc((size_t)N * sizeof(int));
    int*  cursor = (int*) alloc((size_t)N * sizeof(int));
    int*  bsum   = (int*) alloc(256 * sizeof(int));
    int*  nstart = (int*) alloc((size_t)(NBLK + 1) * sizeof(int));
    int*  estart = (int*) alloc((size_t)(NBLK + 1) * sizeof(int));
    int2* sd     = (int2*)alloc((size_t)E * sizeof(int2));
    f16*  ea16   = (f16*) alloc((size_t)E * K1 * sizeof(f16));

    const int nH    = (N + NB - 1) / NB;      // 1563
    const int nscan = (N + 255) / 256;        // 196 <= 256

    hipMemsetAsync(counts, 0, (size_t)N * sizeof(int), stream);

    // fused: compute_h + convert_weights + hist
    prep1_kernel<<<nH + 96 + 2048, 256, 0, stream>>>(
        x, dW, db, h, N, nH, fW1, fW2, Wt1, Wt2, dst, counts, E);

    scan1_kernel<<<nscan, 256, 0, stream>>>(counts, ofs, bsum, N);
    scan2_kernel<<<1, 256, 0, stream>>>(bsum, nscan);
    scan3_kernel<<<nscan, 256, 0, stream>>>(ofs, cursor, bsum, N);

    ranges_kernel<<<(NBLK + 256) / 256, 256, 0, stream>>>(ofs, nstart, estart, N, E, NBLK);

    // fused: scatter + ea convert/permute
    build_kernel<<<2048, 256, 0, stream>>>(ea, src, dst, cursor, sd, ea16, E);

    edge_fused_kernel<<<NBLK, 256, 0, stream>>>(
        ea16, sd, Wt1, Wt2, fb1, fb2, h, out, nstart, estart);

    update_kernel<<<nH, 256, 0, stream>>>(
        x, uW1, ub1, uW2, ub2, out, N);
}